// Round 4
// baseline (235.908 us; speedup 1.0000x reference)
//
#include <hip/hip_runtime.h>
#include <stdint.h>

typedef __bf16 bf16;
typedef __bf16 bf16x8 __attribute__((ext_vector_type(8)));
typedef float f32x4 __attribute__((ext_vector_type(4)));

#define MFMA16(a, b, c) __builtin_amdgcn_mfma_f32_16x16x32_bf16((a), (b), (c), 0, 0, 0)

// async global->LDS DMA, 16B per lane. LDS dest wave-uniform; HW writes base + lane*16.
__device__ __forceinline__ void ldsdma16(const void* g, void* l) {
  __builtin_amdgcn_global_load_lds((const __attribute__((address_space(1))) void*)g,
                                   (__attribute__((address_space(3))) void*)l, 16, 0, 0);
}

// ---------------------------------------------------------------------------
// prep (merged): z<4 -> transpose-cast W[k][n] fp32 -> WT[n][k] bf16
//                z==4 -> cast x fp32 -> bf16
// ---------------------------------------------------------------------------
__global__ __launch_bounds__(256) void prep_kernel(const float* __restrict__ x,
                                                   const float* __restrict__ Wq,
                                                   const float* __restrict__ Wk,
                                                   const float* __restrict__ Wv,
                                                   const float* __restrict__ Wo,
                                                   bf16* __restrict__ WT,
                                                   bf16* __restrict__ xb) {
  if (blockIdx.z == 4) {
    const int t = (blockIdx.y * 16 + blockIdx.x) * 256 + threadIdx.x;  // 0..65535
#pragma unroll
    for (int it = 0; it < 16; ++it) {
      const int idx = (it * 65536 + t) * 4;
      float4 v = *(const float4*)(x + idx);
      union { bf16 h[4]; uint2 u; } p;
      p.h[0] = (bf16)v.x; p.h[1] = (bf16)v.y; p.h[2] = (bf16)v.z; p.h[3] = (bf16)v.w;
      *(uint2*)(xb + idx) = p.u;
    }
    return;
  }
  __shared__ float tile[64][65];
  const float* src = blockIdx.z == 0 ? Wq : blockIdx.z == 1 ? Wk : blockIdx.z == 2 ? Wv : Wo;
  bf16* dst = WT + (size_t)blockIdx.z * 1024 * 1024;
  const int k0 = blockIdx.y * 64, n0 = blockIdx.x * 64;
  const int rr = threadIdx.x >> 6, c = threadIdx.x & 63;
#pragma unroll
  for (int i = 0; i < 16; ++i) {
    int r = i * 4 + rr;
    tile[r][c] = src[(size_t)(k0 + r) * 1024 + n0 + c];
  }
  __syncthreads();
#pragma unroll
  for (int i = 0; i < 16; ++i) {
    int r = i * 4 + rr;
    dst[(size_t)(n0 + r) * 1024 + k0 + c] = (bf16)tile[c][r];
  }
}

// ---------------------------------------------------------------------------
// QKV GEMM, weight-stationary: only B (WT rows) staged in LDS (32 KB phase
// buffer, 8 phases of K=128); A fragments read DIRECTLY from global as 16B
// bf16x8 (L1 serves quad/wave re-reads). Within a phase: 4 barrier-free
// k-steps x 16 independent MFMA. 128x128 tile, grid 24x32 = 768 = 3/CU exact.
// LDS chunks swizzled (low3 ^ row&7) -> frag ds_read_b128 conflict-free-ish,
// DMA dest stays linear (wave-uniform base + lane*16).
// ---------------------------------------------------------------------------
__global__ __launch_bounds__(256) void qkv_gemm(const bf16* __restrict__ xb,
                                                const bf16* __restrict__ WT,
                                                const float* __restrict__ bq,
                                                const float* __restrict__ bk,
                                                const float* __restrict__ bv,
                                                bf16* __restrict__ QKVc) {
  __shared__ bf16 Bs[128 * 128] __attribute__((aligned(16)));  // 32 KB, 16 chunks/row
  const int tid = threadIdx.x, lane = tid & 63, wave = tid >> 6;
  const int wm = wave >> 1, wn = wave & 1;
  const int quad = lane >> 4, l16 = lane & 15;
  const int m0 = blockIdx.y * 128, n0 = blockIdx.x * 128;

  f32x4 acc[4][4];
  const f32x4 zero = {0.f, 0.f, 0.f, 0.f};
#pragma unroll
  for (int i = 0; i < 4; ++i)
#pragma unroll
    for (int j = 0; j < 4; ++j) acc[i][j] = zero;

  const bf16* Arow[4];
#pragma unroll
  for (int i = 0; i < 4; ++i)
    Arow[i] = xb + (size_t)(m0 + wm * 64 + i * 16 + l16) * 1024 + quad * 8;

  for (int ph = 0; ph < 8; ++ph) {
    const int kp = ph * 128;
    // stage B phase: 2048 chunks of 16B, 8 DMA insts/thread
#pragma unroll
    for (int inst = 0; inst < 8; ++inst) {
      int d = inst * 256 + wave * 64 + lane;  // dest chunk 0..2047
      int row = d >> 4, dc = d & 15;
      int sc = (dc & 8) | ((dc & 7) ^ (row & 7));
      ldsdma16(WT + (size_t)(n0 + row) * 1024 + kp + sc * 8,
               (char*)Bs + (size_t)(inst * 256 + wave * 64) * 16);
    }
    __syncthreads();
#pragma unroll
    for (int s = 0; s < 4; ++s) {  // k = kp + s*32
      bf16x8 af[4], bfv[4];
#pragma unroll
      for (int i = 0; i < 4; ++i) {
        af[i] = *(const bf16x8*)(Arow[i] + kp + s * 32);
        int rb = wn * 64 + i * 16 + l16;
        int c = s * 4 + quad;
        int dc = (c & 8) | ((c & 7) ^ (rb & 7));
        bfv[i] = ((const bf16x8*)Bs)[rb * 16 + dc];
      }
#pragma unroll
      for (int i = 0; i < 4; ++i)
#pragma unroll
        for (int j = 0; j < 4; ++j) acc[i][j] = MFMA16(af[i], bfv[j], acc[i][j]);
    }
    __syncthreads();
  }

  // epilogue: block-uniform sel (n-tile of 128 never straddles Q/K/V)
  const int sel = blockIdx.x >> 3;  // 0:Q 1:K 2:V
  const float* bp = sel == 0 ? bq : sel == 1 ? bk : bv;
  const float scl = (sel == 0) ? 0.18033688f : 1.f;  // 0.125 * log2(e)
#pragma unroll
  for (int j = 0; j < 4; ++j) {
    const int n = n0 + wn * 64 + j * 16 + l16;
    const float bias = bp[n & 1023];
#pragma unroll
    for (int i = 0; i < 4; ++i) {
#pragma unroll
      for (int r = 0; r < 4; ++r) {
        const int token = m0 + wm * 64 + i * 16 + quad * 4 + r;
        QKVc[(size_t)token * 3072 + n] = (bf16)((acc[i][j][r] + bias) * scl);
      }
    }
  }
}

// ---------------------------------------------------------------------------
// V transpose: QKVc[:, 2048:3072] -> Vt[b,h,hd,s]. 64x64 tiles via LDS.
// ---------------------------------------------------------------------------
__global__ __launch_bounds__(256) void v_transpose(const bf16* __restrict__ QKVc,
                                                   bf16* __restrict__ Vt) {
  __shared__ bf16 tile[64][72] __attribute__((aligned(16)));
  const int tid = threadIdx.x;
  const int st = blockIdx.x, h = blockIdx.y, b = blockIdx.z;
  {
    const int t = tid >> 2, cg = (tid & 3) * 16;
    const bf16* src = QKVc + ((size_t)(b * 2048 + st * 64 + t)) * 3072 + 2048 + h * 64 + cg;
    bf16x8 v0 = *(const bf16x8*)src;
    bf16x8 v1 = *(const bf16x8*)(src + 8);
    *(bf16x8*)&tile[t][cg] = v0;
    *(bf16x8*)&tile[t][cg + 8] = v1;
  }
  __syncthreads();
  const int hd = tid & 63, sg = (tid >> 6) * 16;
  bf16 o[16];
#pragma unroll
  for (int i = 0; i < 16; ++i) o[i] = tile[sg + i][hd];
  bf16* dst = Vt + ((size_t)((b * 16 + h) * 64 + hd)) * 2048 + st * 64 + sg;
  *(bf16x8*)dst = *(bf16x8*)&o[0];
  *(bf16x8*)(dst + 8) = *(bf16x8*)&o[8];
}

// ---------------------------------------------------------------------------
// Sliding-window attention. 1 block = (b,h,64-query tile), 4 waves x 16 rows.
// Q,K read directly from QKVc C-layout (16B-aligned frags); V from Vt.
// exp2-domain softmax (scale*log2e folded into Q), no max-tracking.
// V frag loads issued BEFORE the P LDS round-trip so they cover exp+LDS latency.
// ---------------------------------------------------------------------------
__global__ __launch_bounds__(256) void attn_kernel(const bf16* __restrict__ QKVc,
                                                   const bf16* __restrict__ Vt,
                                                   bf16* __restrict__ Ao) {
  __shared__ bf16 Ps[4][16 * 72] __attribute__((aligned(16)));  // per-wave P scratch

  const int tid = threadIdx.x, lane = tid & 63, wave = tid >> 6;
  const int quad = lane >> 4, l16 = lane & 15;
  const int qt = blockIdx.x, h = blockIdx.y, b = blockIdx.z;
  const int q0 = qt * 64;
  const bf16* Vb = Vt + ((size_t)(b * 16 + h)) * 2048 * 64;  // [HD][S]

  // Q A-fragments straight from C layout
  const int qrow = wave * 16 + l16;
  const bf16* qp = QKVc + (size_t)(b * 2048 + q0 + qrow) * 3072 + h * 64 + quad * 8;
  const bf16x8 qa0 = *(const bf16x8*)qp;
  const bf16x8 qa1 = *(const bf16x8*)(qp + 32);

  float lrow[4];
  f32x4 oacc[4];
  const f32x4 zero = {0.f, 0.f, 0.f, 0.f};
#pragma unroll
  for (int r = 0; r < 4; ++r) lrow[r] = 0.f;
#pragma unroll
  for (int t = 0; t < 4; ++t) oacc[t] = zero;

  const int clo = (qt >= 4) ? (qt - 4) : 0;
  for (int ck = clo; ck <= qt; ++ck) {
    const int c0 = ck * 64;

    // scores (log2-domain); K B-frags direct from C layout (col offset +1024)
    f32x4 sc[4];
#pragma unroll
    for (int nt = 0; nt < 4; ++nt) {
      const bf16* kp = QKVc + (size_t)(b * 2048 + c0 + nt * 16 + l16) * 3072 + 1024 + h * 64 + quad * 8;
      bf16x8 kb0 = *(const bf16x8*)kp;
      bf16x8 kb1 = *(const bf16x8*)(kp + 32);
      f32x4 s = MFMA16(qa0, kb0, zero);
      sc[nt] = MFMA16(qa1, kb1, s);
    }

    // issue V^T frag loads NOW (independent of softmax/P) so they overlap it
    bf16x8 vb0[4], vb1[4];
#pragma unroll
    for (int ht = 0; ht < 4; ++ht) {
      const bf16* vp = Vb + (size_t)(ht * 16 + l16) * 2048 + c0 + quad * 8;
      vb0[ht] = *(const bf16x8*)vp;
      vb1[ht] = *(const bf16x8*)(vp + 32);
    }

    // softmax: p = exp2(s) (v_exp_f32), masks only on first/last chunk
    if (ck == qt) {  // causal: j <= i
#pragma unroll
      for (int r = 0; r < 4; ++r) {
        const int i = q0 + wave * 16 + quad * 4 + r;
#pragma unroll
        for (int nt = 0; nt < 4; ++nt) {
          const int j = c0 + nt * 16 + l16;
          const float p = (j <= i) ? exp2f(sc[nt][r]) : 0.f;
          sc[nt][r] = p;
          lrow[r] += p;
        }
      }
    } else if (qt >= 4 && ck == qt - 4) {  // window: j >= i-255
#pragma unroll
      for (int r = 0; r < 4; ++r) {
        const int i = q0 + wave * 16 + quad * 4 + r;
#pragma unroll
        for (int nt = 0; nt < 4; ++nt) {
          const int j = c0 + nt * 16 + l16;
          const float p = (j + 255 >= i) ? exp2f(sc[nt][r]) : 0.f;
          sc[nt][r] = p;
          lrow[r] += p;
        }
      }
    } else {
#pragma unroll
      for (int r = 0; r < 4; ++r) {
#pragma unroll
        for (int nt = 0; nt < 4; ++nt) {
          const float p = exp2f(sc[nt][r]);
          sc[nt][r] = p;
          lrow[r] += p;
        }
      }
    }

    // P: C-layout -> A-layout via per-wave LDS round-trip
#pragma unroll
    for (int nt = 0; nt < 4; ++nt)
#pragma unroll
      for (int r = 0; r < 4; ++r)
        Ps[wave][(quad * 4 + r) * 72 + nt * 16 + l16] = (bf16)sc[nt][r];
    asm volatile("s_waitcnt lgkmcnt(0)" ::: "memory");  // same-wave LDS RAW
    bf16x8 pa0 = ((const bf16x8*)Ps[wave])[l16 * 9 + quad];
    bf16x8 pa1 = ((const bf16x8*)Ps[wave])[l16 * 9 + 4 + quad];

    // O += P V
#pragma unroll
    for (int ht = 0; ht < 4; ++ht) {
      f32x4 o = MFMA16(pa0, vb0[ht], oacc[ht]);
      oacc[ht] = MFMA16(pa1, vb1[ht], o);
    }
  }

  // epilogue: one row-sum reduction, normalize, write [B,S,DIM] bf16
#pragma unroll
  for (int r = 0; r < 4; ++r) {
#pragma unroll
    for (int m = 8; m >= 1; m >>= 1) lrow[r] += __shfl_xor(lrow[r], m, 64);
    const float inv = 1.f / lrow[r];
    const int row = q0 + wave * 16 + quad * 4 + r;
    const size_t outb = ((size_t)(b * 2048 + row)) * 1024 + h * 64;
#pragma unroll
    for (int ht = 0; ht < 4; ++ht)
      Ao[outb + ht * 16 + l16] = (bf16)(oacc[ht][r] * inv);
  }
}

// ---------------------------------------------------------------------------
// Output GEMM, weight-stationary like qkv: Ao[4096,1024] @ Wo + bo -> fp32.
// BM=64, BN=128, grid 8x64 = 512 = 2/CU exact. LDS 32 KB phase buffer.
// Waves 2x2: each 32 rows x 64 cols (2x4 mfma tiles).
// ---------------------------------------------------------------------------
__global__ __launch_bounds__(256) void out_gemm(const bf16* __restrict__ Ain,
                                                const bf16* __restrict__ WoT,
                                                const float* __restrict__ bo,
                                                float* __restrict__ out) {
  __shared__ bf16 Bs[128 * 128] __attribute__((aligned(16)));  // 32 KB
  const int tid = threadIdx.x, lane = tid & 63, wave = tid >> 6;
  const int wm = wave >> 1, wn = wave & 1;
  const int quad = lane >> 4, l16 = lane & 15;
  const int m0 = blockIdx.y * 64, n0 = blockIdx.x * 128;

  f32x4 acc[2][4];
  const f32x4 zero = {0.f, 0.f, 0.f, 0.f};
#pragma unroll
  for (int i = 0; i < 2; ++i)
#pragma unroll
    for (int j = 0; j < 4; ++j) acc[i][j] = zero;

  const bf16* Arow[2];
#pragma unroll
  for (int i = 0; i < 2; ++i)
    Arow[i] = Ain + (size_t)(m0 + wm * 32 + i * 16 + l16) * 1024 + quad * 8;

  for (int ph = 0; ph < 8; ++ph) {
    const int kp = ph * 128;
#pragma unroll
    for (int inst = 0; inst < 8; ++inst) {
      int d = inst * 256 + wave * 64 + lane;
      int row = d >> 4, dc = d & 15;
      int sc = (dc & 8) | ((dc & 7) ^ (row & 7));
      ldsdma16(WoT + (size_t)(n0 + row) * 1024 + kp + sc * 8,
               (char*)Bs + (size_t)(inst * 256 + wave * 64) * 16);
    }
    __syncthreads();
#pragma unroll
    for (int s = 0; s < 4; ++s) {
      bf16x8 af[2], bfv[4];
#pragma unroll
      for (int i = 0; i < 2; ++i) af[i] = *(const bf16x8*)(Arow[i] + kp + s * 32);
#pragma unroll
      for (int j = 0; j < 4; ++j) {
        int rb = wn * 64 + j * 16 + l16;
        int c = s * 4 + quad;
        int dc = (c & 8) | ((c & 7) ^ (rb & 7));
        bfv[j] = ((const bf16x8*)Bs)[rb * 16 + dc];
      }
#pragma unroll
      for (int i = 0; i < 2; ++i)
#pragma unroll
        for (int j = 0; j < 4; ++j) acc[i][j] = MFMA16(af[i], bfv[j], acc[i][j]);
    }
    __syncthreads();
  }

#pragma unroll
  for (int j = 0; j < 4; ++j) {
    const int n = n0 + wn * 64 + j * 16 + l16;
    const float bias = bo[n];
#pragma unroll
    for (int i = 0; i < 2; ++i) {
#pragma unroll
      for (int r = 0; r < 4; ++r) {
        const int token = m0 + wm * 32 + i * 16 + quad * 4 + r;
        out[(size_t)token * 1024 + n] = acc[i][j][r] + bias;
      }
    }
  }
}

// ---------------------------------------------------------------------------
extern "C" void kernel_launch(void* const* d_in, const int* in_sizes, int n_in,
                              void* d_out, int out_size, void* d_ws, size_t ws_size,
                              hipStream_t stream) {
  const float* x  = (const float*)d_in[0];
  const float* Wq = (const float*)d_in[1];
  const float* bq = (const float*)d_in[2];
  const float* Wk = (const float*)d_in[3];
  const float* bk = (const float*)d_in[4];
  const float* Wv = (const float*)d_in[5];
  const float* bv = (const float*)d_in[6];
  const float* Wo = (const float*)d_in[7];
  const float* bo = (const float*)d_in[8];
  float* out = (float*)d_out;

  char* ws = (char*)d_ws;
  bf16* xb   = (bf16*)(ws);                      //  8 MB  x bf16
  bf16* WT   = (bf16*)(ws + ((size_t)8 << 20));  //  8 MB  WqT|WkT|WvT|WoT bf16 [n][k]
  bf16* QKVc = (bf16*)(ws + ((size_t)16 << 20)); // 24 MB  [4096][3072] C layout
  bf16* Vt   = (bf16*)(ws + ((size_t)40 << 20)); //  8 MB  [B,H,HD,S]
  bf16* Ao   = (bf16*)(ws + ((size_t)48 << 20)); //  8 MB  [B,S,DIM]

  prep_kernel<<<dim3(16, 16, 5), 256, 0, stream>>>(x, Wq, Wk, Wv, Wo, WT, xb);
  qkv_gemm<<<dim3(24, 32), 256, 0, stream>>>(xb, WT, bq, bk, bv, QKVc);
  v_transpose<<<dim3(32, 16, 2), 256, 0, stream>>>(QKVc, Vt);
  attn_kernel<<<dim3(32, 16, 2), 256, 0, stream>>>(QKVc, Vt, Ao);
  out_gemm<<<dim3(8, 64), 256, 0, stream>>>(Ao, WT + (size_t)3 * 1024 * 1024, bo, out);
}

// Round 5
// 176.101 us; speedup vs baseline: 1.3396x; 1.3396x over previous
//
#include <hip/hip_runtime.h>
#include <stdint.h>

typedef __bf16 bf16;
typedef __bf16 bf16x8 __attribute__((ext_vector_type(8)));
typedef float f32x4 __attribute__((ext_vector_type(4)));

#define MFMA16(a, b, c) __builtin_amdgcn_mfma_f32_16x16x32_bf16((a), (b), (c), 0, 0, 0)

// async global->LDS DMA, 16B per lane. LDS dest wave-uniform; HW writes base + lane*16.
__device__ __forceinline__ void ldsdma16(const void* g, void* l) {
  __builtin_amdgcn_global_load_lds((const __attribute__((address_space(1))) void*)g,
                                   (__attribute__((address_space(3))) void*)l, 16, 0, 0);
}

// ---------------------------------------------------------------------------
// prep (merged): z<4 -> transpose-cast W[k][n] fp32 -> WT[n][k] bf16
//                z==4 -> cast x fp32 -> bf16
// ---------------------------------------------------------------------------
__global__ __launch_bounds__(256) void prep_kernel(const float* __restrict__ x,
                                                   const float* __restrict__ Wq,
                                                   const float* __restrict__ Wk,
                                                   const float* __restrict__ Wv,
                                                   const float* __restrict__ Wo,
                                                   bf16* __restrict__ WT,
                                                   bf16* __restrict__ xb) {
  if (blockIdx.z == 4) {
    const int t = (blockIdx.y * 16 + blockIdx.x) * 256 + threadIdx.x;  // 0..65535
#pragma unroll
    for (int it = 0; it < 16; ++it) {
      const int idx = (it * 65536 + t) * 4;
      float4 v = *(const float4*)(x + idx);
      union { bf16 h[4]; uint2 u; } p;
      p.h[0] = (bf16)v.x; p.h[1] = (bf16)v.y; p.h[2] = (bf16)v.z; p.h[3] = (bf16)v.w;
      *(uint2*)(xb + idx) = p.u;
    }
    return;
  }
  __shared__ float tile[64][65];
  const float* src = blockIdx.z == 0 ? Wq : blockIdx.z == 1 ? Wk : blockIdx.z == 2 ? Wv : Wo;
  bf16* dst = WT + (size_t)blockIdx.z * 1024 * 1024;
  const int k0 = blockIdx.y * 64, n0 = blockIdx.x * 64;
  const int rr = threadIdx.x >> 6, c = threadIdx.x & 63;
#pragma unroll
  for (int i = 0; i < 16; ++i) {
    int r = i * 4 + rr;
    tile[r][c] = src[(size_t)(k0 + r) * 1024 + n0 + c];
  }
  __syncthreads();
#pragma unroll
  for (int i = 0; i < 16; ++i) {
    int r = i * 4 + rr;
    dst[(size_t)(n0 + r) * 1024 + k0 + c] = (bf16)tile[c][r];
  }
}

// ---------------------------------------------------------------------------
// QKV GEMM (round-3 proven: 45 us, 0 conflicts), BK=64, both operands in LDS:
// xb[4096,1024] @ Wqkv -> QKVc [4096][3072]. sel block-uniform; Q gets
// 0.125*log2(e) (exp2-domain softmax). 8-chunk rows, swizzle c^(row&7).
// ---------------------------------------------------------------------------
__global__ __launch_bounds__(256) void qkv_gemm(const bf16* __restrict__ xb,
                                                const bf16* __restrict__ WT,
                                                const float* __restrict__ bq,
                                                const float* __restrict__ bk,
                                                const float* __restrict__ bv,
                                                bf16* __restrict__ QKVc) {
  __shared__ bf16 As[128 * 64] __attribute__((aligned(16)));
  __shared__ bf16 Bs[128 * 64] __attribute__((aligned(16)));
  const int tid = threadIdx.x, lane = tid & 63, wave = tid >> 6;
  const int wm = wave >> 1, wn = wave & 1;
  const int quad = lane >> 4, l16 = lane & 15;
  const int m0 = blockIdx.y * 128, n0 = blockIdx.x * 128;

  f32x4 acc[4][4];
  const f32x4 zero = {0.f, 0.f, 0.f, 0.f};
#pragma unroll
  for (int i = 0; i < 4; ++i)
#pragma unroll
    for (int j = 0; j < 4; ++j) acc[i][j] = zero;

  for (int k0 = 0; k0 < 1024; k0 += 64) {
#pragma unroll
    for (int b2 = 0; b2 < 4; ++b2) {
      int chunk = wave * 256 + b2 * 64 + lane;  // 0..1023
      int row = chunk >> 3;
      int cg = (chunk & 7) ^ (row & 7);
      ldsdma16(xb + (size_t)(m0 + row) * 1024 + k0 + cg * 8,
               (char*)As + (size_t)(wave * 256 + b2 * 64) * 16);
      ldsdma16(WT + (size_t)(n0 + row) * 1024 + k0 + cg * 8,
               (char*)Bs + (size_t)(wave * 256 + b2 * 64) * 16);
    }
    __syncthreads();
#pragma unroll
    for (int s = 0; s < 2; ++s) {
      bf16x8 af[4], bfv[4];
#pragma unroll
      for (int i = 0; i < 4; ++i) {
        int ra = wm * 64 + i * 16 + l16;
        af[i] = ((const bf16x8*)As)[ra * 8 + ((s * 4 + quad) ^ (ra & 7))];
        int rb = wn * 64 + i * 16 + l16;
        bfv[i] = ((const bf16x8*)Bs)[rb * 8 + ((s * 4 + quad) ^ (rb & 7))];
      }
#pragma unroll
      for (int i = 0; i < 4; ++i)
#pragma unroll
        for (int j = 0; j < 4; ++j) acc[i][j] = MFMA16(af[i], bfv[j], acc[i][j]);
    }
    __syncthreads();
  }

  const int sel = blockIdx.x >> 3;  // 0:Q 1:K 2:V
  const float* bp = sel == 0 ? bq : sel == 1 ? bk : bv;
  const float scl = (sel == 0) ? 0.18033688f : 1.f;  // 0.125 * log2(e)
#pragma unroll
  for (int j = 0; j < 4; ++j) {
    const int n = n0 + wn * 64 + j * 16 + l16;
    const float bias = bp[n & 1023];
#pragma unroll
    for (int i = 0; i < 4; ++i) {
#pragma unroll
      for (int r = 0; r < 4; ++r) {
        const int token = m0 + wm * 64 + i * 16 + quad * 4 + r;
        QKVc[(size_t)token * 3072 + n] = (bf16)((acc[i][j][r] + bias) * scl);
      }
    }
  }
}

// ---------------------------------------------------------------------------
// V transpose: QKVc[:, 2048:3072] -> Vt[b,h,hd,s]. 64x64 tiles via LDS.
// ---------------------------------------------------------------------------
__global__ __launch_bounds__(256) void v_transpose(const bf16* __restrict__ QKVc,
                                                   bf16* __restrict__ Vt) {
  __shared__ bf16 tile[64][72] __attribute__((aligned(16)));
  const int tid = threadIdx.x;
  const int st = blockIdx.x, h = blockIdx.y, b = blockIdx.z;
  {
    const int t = tid >> 2, cg = (tid & 3) * 16;
    const bf16* src = QKVc + ((size_t)(b * 2048 + st * 64 + t)) * 3072 + 2048 + h * 64 + cg;
    bf16x8 v0 = *(const bf16x8*)src;
    bf16x8 v1 = *(const bf16x8*)(src + 8);
    *(bf16x8*)&tile[t][cg] = v0;
    *(bf16x8*)&tile[t][cg + 8] = v1;
  }
  __syncthreads();
  const int hd = tid & 63, sg = (tid >> 6) * 16;
  bf16 o[16];
#pragma unroll
  for (int i = 0; i < 16; ++i) o[i] = tile[sg + i][hd];
  bf16* dst = Vt + ((size_t)((b * 16 + h) * 64 + hd)) * 2048 + st * 64 + sg;
  *(bf16x8*)dst = *(bf16x8*)&o[0];
  *(bf16x8*)(dst + 8) = *(bf16x8*)&o[8];
}

// ---------------------------------------------------------------------------
// Sliding-window attention, DMA-staged + double-buffered K/V.
// 1 block = (b, h, 128-query tile); 4 waves x 32 query rows (2 row-tiles).
// Key chunks of 64: ck in [max(0,2qt-4), 2qt+1] (<=6). K and V^T staged into
// LDS via global_load_lds with conflict-free 8-chunk-row XOR swizzle; chunk
// ck+1 staged while computing ck (single barrier per chunk: its vmcnt drain
// IS the prefetch wait). exp2-domain no-max softmax; masks only on
// ck>=2qt (causal) / ck<=2qt-3 (window).
// ---------------------------------------------------------------------------
__global__ __launch_bounds__(256) void attn_kernel(const bf16* __restrict__ QKVc,
                                                   const bf16* __restrict__ VtG,
                                                   bf16* __restrict__ Ao) {
  __shared__ bf16 Qs[128 * 64] __attribute__((aligned(16)));     // 16 KB
  __shared__ bf16 Ks[2][64 * 64] __attribute__((aligned(16)));   // 16 KB
  __shared__ bf16 Vs[2][64 * 64] __attribute__((aligned(16)));   // 16 KB
  __shared__ bf16 Ps[4][2][16 * 72] __attribute__((aligned(16)));// 18 KB

  const int tid = threadIdx.x, lane = tid & 63, wave = tid >> 6;
  const int quad = lane >> 4, l16 = lane & 15;
  const int qt = blockIdx.x, h = blockIdx.y, b = blockIdx.z;
  const int q0 = qt * 128;
  const size_t vbase = (size_t)(b * 16 + h) * 131072;  // [HD][S] head base

  // stage Q tile: 1024 chunks, swizzle cc ^ (row&7)
#pragma unroll
  for (int inst = 0; inst < 4; ++inst) {
    int d = inst * 256 + wave * 64 + lane;
    int row = d >> 3, cc = d & 7;
    ldsdma16(QKVc + (size_t)(b * 2048 + q0 + row) * 3072 + h * 64 + ((cc ^ (row & 7)) * 8),
             (char*)Qs + (size_t)(inst * 256 + wave * 64) * 16);
  }

  const int lo = (qt >= 2) ? (2 * qt - 4) : 0;
  const int hi = 2 * qt + 1;

  // stage K/V chunk ck into buffer bu
  auto stage_kv = [&](int ck, int bu) {
    const int c0k = ck * 64;
#pragma unroll
    for (int inst = 0; inst < 2; ++inst) {
      int d = inst * 256 + wave * 64 + lane;
      int row = d >> 3, cc = d & 7;
      int sc = (cc ^ (row & 7)) * 8;
      ldsdma16(QKVc + (size_t)(b * 2048 + c0k + row) * 3072 + 1024 + h * 64 + sc,
               (char*)Ks[bu] + (size_t)(inst * 256 + wave * 64) * 16);
      ldsdma16(VtG + vbase + (size_t)row * 2048 + c0k + sc,
               (char*)Vs[bu] + (size_t)(inst * 256 + wave * 64) * 16);
    }
  };

  stage_kv(lo, lo & 1);
  __syncthreads();  // Q + first K/V staged

  // Q A-fragments from LDS
  bf16x8 qa[2][2];
#pragma unroll
  for (int rt = 0; rt < 2; ++rt) {
    int row = wave * 32 + rt * 16 + l16;
#pragma unroll
    for (int s = 0; s < 2; ++s)
      qa[rt][s] = ((const bf16x8*)Qs)[row * 8 + ((s * 4 + quad) ^ (row & 7))];
  }

  float lrow[2][4];
  f32x4 oacc[2][4];
  const f32x4 zero = {0.f, 0.f, 0.f, 0.f};
#pragma unroll
  for (int rt = 0; rt < 2; ++rt)
#pragma unroll
    for (int r = 0; r < 4; ++r) { lrow[rt][r] = 0.f; oacc[rt][r] = zero; }

  for (int ck = lo; ck <= hi; ++ck) {
    if (ck > lo) __syncthreads();            // drains stage(ck) DMA; protects buf reuse
    if (ck < hi) stage_kv(ck + 1, (ck + 1) & 1);  // prefetch under compute
    const int bu = ck & 1;
    const int c0 = ck * 64;

    // K / V^T B-fragments from LDS
    bf16x8 kb[4][2], vb[4][2];
#pragma unroll
    for (int nt = 0; nt < 4; ++nt) {
      int rr = nt * 16 + l16;
#pragma unroll
      for (int s = 0; s < 2; ++s) {
        kb[nt][s] = ((const bf16x8*)Ks[bu])[rr * 8 + ((s * 4 + quad) ^ (rr & 7))];
        vb[nt][s] = ((const bf16x8*)Vs[bu])[rr * 8 + ((s * 4 + quad) ^ (rr & 7))];
      }
    }

#pragma unroll
    for (int rt = 0; rt < 2; ++rt) {
      // scores (log2-domain, scale folded into Q)
      f32x4 sc4[4];
#pragma unroll
      for (int nt = 0; nt < 4; ++nt) {
        f32x4 s = MFMA16(qa[rt][0], kb[nt][0], zero);
        sc4[nt] = MFMA16(qa[rt][1], kb[nt][1], s);
      }

      // softmax: p = exp2(s); masks only where needed
      if (ck >= 2 * qt) {  // diagonal chunks: causal j <= i
#pragma unroll
        for (int r = 0; r < 4; ++r) {
          const int i = q0 + wave * 32 + rt * 16 + quad * 4 + r;
#pragma unroll
          for (int nt = 0; nt < 4; ++nt) {
            const int j = c0 + nt * 16 + l16;
            const float p = (j <= i) ? exp2f(sc4[nt][r]) : 0.f;
            sc4[nt][r] = p;
            lrow[rt][r] += p;
          }
        }
      } else if (ck <= 2 * qt - 3) {  // trailing chunks: window j >= i-255
#pragma unroll
        for (int r = 0; r < 4; ++r) {
          const int i = q0 + wave * 32 + rt * 16 + quad * 4 + r;
#pragma unroll
          for (int nt = 0; nt < 4; ++nt) {
            const int j = c0 + nt * 16 + l16;
            const float p = (j + 255 >= i) ? exp2f(sc4[nt][r]) : 0.f;
            sc4[nt][r] = p;
            lrow[rt][r] += p;
          }
        }
      } else {  // fully valid
#pragma unroll
        for (int r = 0; r < 4; ++r) {
#pragma unroll
          for (int nt = 0; nt < 4; ++nt) {
            const float p = exp2f(sc4[nt][r]);
            sc4[nt][r] = p;
            lrow[rt][r] += p;
          }
        }
      }

      // P: C-layout -> A-layout via per-wave/rt LDS scratch
#pragma unroll
      for (int nt = 0; nt < 4; ++nt)
#pragma unroll
        for (int r = 0; r < 4; ++r)
          Ps[wave][rt][(quad * 4 + r) * 72 + nt * 16 + l16] = (bf16)sc4[nt][r];
      asm volatile("s_waitcnt lgkmcnt(0)" ::: "memory");  // same-wave LDS RAW
      bf16x8 pa0 = ((const bf16x8*)Ps[wave][rt])[l16 * 9 + quad];
      bf16x8 pa1 = ((const bf16x8*)Ps[wave][rt])[l16 * 9 + 4 + quad];

      // O += P V
#pragma unroll
      for (int ht = 0; ht < 4; ++ht) {
        f32x4 o = MFMA16(pa0, vb[ht][0], oacc[rt][ht]);
        oacc[rt][ht] = MFMA16(pa1, vb[ht][1], o);
      }
    }
  }

  // epilogue: row-sum reduce across l16, normalize, write [B,S,DIM] bf16
#pragma unroll
  for (int rt = 0; rt < 2; ++rt) {
#pragma unroll
    for (int r = 0; r < 4; ++r) {
      float lr = lrow[rt][r];
#pragma unroll
      for (int m = 8; m >= 1; m >>= 1) lr += __shfl_xor(lr, m, 64);
      const float inv = 1.f / lr;
      const int row = q0 + wave * 32 + rt * 16 + quad * 4 + r;
      const size_t outb = ((size_t)(b * 2048 + row)) * 1024 + h * 64;
#pragma unroll
      for (int ht = 0; ht < 4; ++ht)
        Ao[outb + ht * 16 + l16] = (bf16)(oacc[rt][ht][r] * inv);
    }
  }
}

// ---------------------------------------------------------------------------
// Output GEMM (round-3 proven), BK=64: Ao[4096,1024] @ Wo + bo -> fp32.
// 128x64 tiles, 512 blocks (2/CU). Waves 2x2: 64 rows x 32 cols each.
// ---------------------------------------------------------------------------
__global__ __launch_bounds__(256) void out_gemm(const bf16* __restrict__ Ain,
                                                const bf16* __restrict__ WoT,
                                                const float* __restrict__ bo,
                                                float* __restrict__ out) {
  __shared__ bf16 As[128 * 64] __attribute__((aligned(16)));  // 1024 chunks
  __shared__ bf16 Bs[64 * 64] __attribute__((aligned(16)));   // 512 chunks
  const int tid = threadIdx.x, lane = tid & 63, wave = tid >> 6;
  const int wm = wave >> 1, wn = wave & 1;
  const int quad = lane >> 4, l16 = lane & 15;
  const int m0 = blockIdx.y * 128, n0 = blockIdx.x * 64;

  f32x4 acc[4][2];
  const f32x4 zero = {0.f, 0.f, 0.f, 0.f};
#pragma unroll
  for (int i = 0; i < 4; ++i)
#pragma unroll
    for (int j = 0; j < 2; ++j) acc[i][j] = zero;

  for (int k0 = 0; k0 < 1024; k0 += 64) {
#pragma unroll
    for (int b2 = 0; b2 < 4; ++b2) {  // A: 1024 chunks
      int chunk = wave * 256 + b2 * 64 + lane;
      int row = chunk >> 3;
      int cg = (chunk & 7) ^ (row & 7);
      ldsdma16(Ain + (size_t)(m0 + row) * 1024 + k0 + cg * 8,
               (char*)As + (size_t)(wave * 256 + b2 * 64) * 16);
    }
#pragma unroll
    for (int b2 = 0; b2 < 2; ++b2) {  // B: 512 chunks
      int chunk = wave * 128 + b2 * 64 + lane;
      int row = chunk >> 3;
      int cg = (chunk & 7) ^ (row & 7);
      ldsdma16(WoT + (size_t)(n0 + row) * 1024 + k0 + cg * 8,
               (char*)Bs + (size_t)(wave * 128 + b2 * 64) * 16);
    }
    __syncthreads();
#pragma unroll
    for (int s = 0; s < 2; ++s) {
      bf16x8 af[4], bfv[2];
#pragma unroll
      for (int i = 0; i < 4; ++i) {
        int ra = wm * 64 + i * 16 + l16;
        af[i] = ((const bf16x8*)As)[ra * 8 + ((s * 4 + quad) ^ (ra & 7))];
      }
#pragma unroll
      for (int j = 0; j < 2; ++j) {
        int rb = wn * 32 + j * 16 + l16;
        bfv[j] = ((const bf16x8*)Bs)[rb * 8 + ((s * 4 + quad) ^ (rb & 7))];
      }
#pragma unroll
      for (int i = 0; i < 4; ++i)
#pragma unroll
        for (int j = 0; j < 2; ++j) acc[i][j] = MFMA16(af[i], bfv[j], acc[i][j]);
    }
    __syncthreads();
  }

#pragma unroll
  for (int j = 0; j < 2; ++j) {
    const int n = n0 + wn * 32 + j * 16 + l16;
    const float bias = bo[n];
#pragma unroll
    for (int i = 0; i < 4; ++i) {
#pragma unroll
      for (int r = 0; r < 4; ++r) {
        const int token = m0 + wm * 64 + i * 16 + quad * 4 + r;
        out[(size_t)token * 1024 + n] = acc[i][j][r] + bias;
      }
    }
  }
}

// ---------------------------------------------------------------------------
extern "C" void kernel_launch(void* const* d_in, const int* in_sizes, int n_in,
                              void* d_out, int out_size, void* d_ws, size_t ws_size,
                              hipStream_t stream) {
  const float* x  = (const float*)d_in[0];
  const float* Wq = (const float*)d_in[1];
  const float* bq = (const float*)d_in[2];
  const float* Wk = (const float*)d_in[3];
  const float* bk = (const float*)d_in[4];
  const float* Wv = (const float*)d_in[5];
  const float* bv = (const float*)d_in[6];
  const float* Wo = (const float*)d_in[7];
  const float* bo = (const float*)d_in[8];
  float* out = (float*)d_out;

  char* ws = (char*)d_ws;
  bf16* xb   = (bf16*)(ws);                      //  8 MB  x bf16
  bf16* WT   = (bf16*)(ws + ((size_t)8 << 20));  //  8 MB  WqT|WkT|WvT|WoT bf16 [n][k]
  bf16* QKVc = (bf16*)(ws + ((size_t)16 << 20)); // 24 MB  [4096][3072] C layout
  bf16* Vt   = (bf16*)(ws + ((size_t)40 << 20)); //  8 MB  [B,H,HD,S]
  bf16* Ao   = (bf16*)(ws + ((size_t)48 << 20)); //  8 MB  [B,S,DIM]

  prep_kernel<<<dim3(16, 16, 5), 256, 0, stream>>>(x, Wq, Wk, Wv, Wo, WT, xb);
  qkv_gemm<<<dim3(24, 32), 256, 0, stream>>>(xb, WT, bq, bk, bv, QKVc);
  v_transpose<<<dim3(32, 16, 2), 256, 0, stream>>>(QKVc, Vt);
  attn_kernel<<<dim3(16, 16, 2), 256, 0, stream>>>(QKVc, Vt, Ao);
  out_gemm<<<dim3(16, 32), 256, 0, stream>>>(Ao, WT + (size_t)3 * 1024 * 1024, bo, out);
}